// Round 1
// baseline (676.683 us; speedup 1.0000x reference)
//
#include <hip/hip_runtime.h>
#include <hip/hip_bf16.h>
#include <math.h>
#include <stdint.h>

typedef __bf16 bf16_t;
typedef __attribute__((ext_vector_type(8))) __bf16 bf16x8;
typedef __attribute__((ext_vector_type(4))) float f32x4;
typedef unsigned short u16;

#define DEV static __device__ __forceinline__

DEV u16 f2b(float f){ bf16_t h = (bf16_t)f; return __builtin_bit_cast(u16, h); }
DEV float b2f(u16 u){ bf16_t h = __builtin_bit_cast(bf16_t, u); return (float)h; }
DEV f32x4 mfma16(bf16x8 a, bf16x8 b, f32x4 c){
  return __builtin_amdgcn_mfma_f32_16x16x32_bf16(a, b, c, 0, 0, 0);
}

// Problem constants
constexpr int Bc = 2, Sc = 2048, Dc = 1024, Hc = 16;
constexpr int Mc = Bc * Sc;  // 4096

// ---------------- converts ----------------
__global__ __launch_bounds__(256) void k_convert_x(const float* __restrict__ x,
                                                   u16* __restrict__ xh, u16* __restrict__ xl){
  size_t i = ((size_t)blockIdx.x*256 + threadIdx.x)*4;
  float4 v = *(const float4*)(x + i);
  ushort4 hv, lv; float f, hf;
  f=v.x; hv.x=f2b(f); hf=b2f(hv.x); lv.x=f2b(f-hf);
  f=v.y; hv.y=f2b(f); hf=b2f(hv.y); lv.y=f2b(f-hf);
  f=v.z; hv.z=f2b(f); hf=b2f(hv.z); lv.z=f2b(f-hf);
  f=v.w; hv.w=f2b(f); hf=b2f(hv.w); lv.w=f2b(f-hf);
  *(ushort4*)(xh+i) = hv;
  *(ushort4*)(xl+i) = lv;
}

// transpose W [K][N] -> Wt [N][K], split to bf16 hi/lo (z<3) or hi only (z==3: Wo)
__global__ __launch_bounds__(256) void k_convert_w(const float* __restrict__ Wq, const float* __restrict__ Wk,
                                                   const float* __restrict__ Wv, const float* __restrict__ Wo,
                                                   u16* __restrict__ wth, u16* __restrict__ wtl,
                                                   u16* __restrict__ wot){
  __shared__ float tile[64][65];
  int z = blockIdx.z;
  const float* W = (z==0)?Wq:((z==1)?Wk:((z==2)?Wv:Wo));
  int n0 = blockIdx.x*64, k0 = blockIdx.y*64;
  int t = threadIdx.x;
  int r = t>>6, c = t&63;
  #pragma unroll
  for(int i=0;i<16;i++){
    int row = i*4 + r;
    tile[row][c] = W[(size_t)(k0+row)*1024 + n0 + c];
  }
  __syncthreads();
  #pragma unroll
  for(int i=0;i<16;i++){
    int nrow = i*4 + r;
    float v = tile[c][nrow];   // = W[k0+c][n0+nrow]
    size_t o = (size_t)(n0+nrow)*1024 + k0 + c;
    u16 hb = f2b(v);
    if(z<3){
      wth[(size_t)z*1048576 + o] = hb;
      wtl[(size_t)z*1048576 + o] = f2b(v - b2f(hb));
    } else {
      wot[o] = hb;
    }
  }
}

// ---------------- relative position bias ----------------
// biasTab[h][idx], idx = (k-q)+2047 in [0,4094]
__global__ __launch_bounds__(256) void k_bias_table(const float* __restrict__ rel_table,
                                                    float* __restrict__ bt){
  int gid = blockIdx.x*256 + threadIdx.x;   // 16*4096
  int h = gid >> 12, idx = gid & 4095;
  float v = 0.f;
  if(idx < 4095){
    int delta = idx - 2047;   // k - q
    int n = -delta;           // q - k
    int ret = 0;
    if(n < 0){ ret = 16; n = -n; }
    int bucket;
    if(n < 8) bucket = n + ret;
    else {
      // replicate np f32 op sequence: a=f32(ln(n/8)); r=a/f32(ln16); trunc(r*8)
      float a = (float)log((double)n * 0.125);
      float rr = (float)((double)a / (double)2.7725887298583984f);
      int vl = 8 + (int)(rr * 8.0f);
      vl = vl > 15 ? 15 : vl;
      bucket = vl + ret;
    }
    v = rel_table[bucket*16 + h];
  }
  bt[gid] = v;
}

__global__ __launch_bounds__(256) void k_write_bias(const float* __restrict__ bt,
                                                    float* __restrict__ out){
  size_t f = ((size_t)blockIdx.x*256 + threadIdx.x)*4;
  int h = (int)(f >> 22);
  int rem = (int)(f & 4194303);
  int q = rem >> 11;
  int k = rem & 2047;
  const float* row = bt + h*4096 + (k - q + 2047);
  float4 v = make_float4(row[0], row[1], row[2], row[3]);
  *(float4*)(out + f) = v;
}

// ---------------- QKV projection GEMM (split-bf16 x3) ----------------
// C[m][n] = sum_k x[m][k]*W[k][n];  A staged [128][32], B staged from Wt[N][K] as [128][32]
__global__ __launch_bounds__(256) void k_gemm_qkv(const u16* __restrict__ xh, const u16* __restrict__ xl,
                                                  const u16* __restrict__ wth, const u16* __restrict__ wtl,
                                                  u16* __restrict__ qh, u16* __restrict__ ql,
                                                  u16* __restrict__ kh, u16* __restrict__ kl,
                                                  u16* __restrict__ vt){
  __shared__ __align__(16) u16 Ah[128*32];
  __shared__ __align__(16) u16 Al[128*32];
  __shared__ __align__(16) u16 Bh[128*32];
  __shared__ __align__(16) u16 Bl[128*32];
  int z = blockIdx.z;
  const u16* WH = wth + (size_t)z*1048576;
  const u16* WL = wtl + (size_t)z*1048576;
  int m0 = blockIdx.y*128, n0 = blockIdx.x*128;
  int t = threadIdx.x, w = t>>6, lane = t&63, l16 = lane&15, g = lane>>4;
  const f32x4 fzero = {0.f,0.f,0.f,0.f};
  f32x4 acc[4][4];
  #pragma unroll
  for(int i=0;i<4;i++)
    #pragma unroll
    for(int j=0;j<4;j++) acc[i][j] = fzero;
  int rbase = (w>>1)*64, cbase = (w&1)*64;
  for(int k0=0;k0<1024;k0+=32){
    __syncthreads();
    #pragma unroll
    for(int jj=0;jj<2;jj++){
      int c = t + 256*jj;            // [0,512) chunks of 8 bf16
      int row = c>>2, colE = (c&3)*8;
      size_t ga = (size_t)(m0+row)*1024 + k0 + colE;
      size_t gb = (size_t)(n0+row)*1024 + k0 + colE;
      int lo = row*32 + colE;
      *(uint4*)&Ah[lo] = *(const uint4*)&xh[ga];
      *(uint4*)&Al[lo] = *(const uint4*)&xl[ga];
      *(uint4*)&Bh[lo] = *(const uint4*)&WH[gb];
      *(uint4*)&Bl[lo] = *(const uint4*)&WL[gb];
    }
    __syncthreads();
    bf16x8 ah[4], am[4];
    #pragma unroll
    for(int i=0;i<4;i++){
      int off = (rbase + i*16 + l16)*32 + g*8;
      ah[i] = *(const bf16x8*)&Ah[off];
      am[i] = *(const bf16x8*)&Al[off];
    }
    #pragma unroll
    for(int j=0;j<4;j++){
      int off = (cbase + j*16 + l16)*32 + g*8;
      bf16x8 bh = *(const bf16x8*)&Bh[off];
      bf16x8 bl = *(const bf16x8*)&Bl[off];
      #pragma unroll
      for(int i=0;i<4;i++){
        acc[i][j] = mfma16(ah[i], bh, acc[i][j]);
        acc[i][j] = mfma16(ah[i], bl, acc[i][j]);
        acc[i][j] = mfma16(am[i], bh, acc[i][j]);
      }
    }
  }
  // epilogue: C/D layout col=lane&15, row=(lane>>4)*4+reg
  #pragma unroll
  for(int i=0;i<4;i++){
    #pragma unroll
    for(int j=0;j<4;j++){
      #pragma unroll
      for(int r=0;r<4;r++){
        int m = m0 + rbase + i*16 + g*4 + r;
        int n = n0 + cbase + j*16 + l16;
        float v = acc[i][j][r];
        int b = m >> 11, s = m & 2047;
        int hh = n >> 6, d = n & 63;
        if(z==2){
          vt[((size_t)(b*16+hh)*64 + d)*2048 + s] = f2b(v);       // V^T [b][h][d][s]
        } else {
          size_t a = ((size_t)(b*16+hh)*2048 + s)*64 + d;          // [b][h][s][d]
          u16 hb = f2b(v);
          u16 lb = f2b(v - b2f(hb));
          if(z==0){ qh[a]=hb; ql[a]=lb; }
          else    { kh[a]=hb; kl[a]=lb; }
        }
      }
    }
  }
}

// ---------------- flash attention ----------------
__global__ __launch_bounds__(256) void k_attn(const u16* __restrict__ qh, const u16* __restrict__ ql,
                                              const u16* __restrict__ kh, const u16* __restrict__ kl,
                                              const u16* __restrict__ vt, const float* __restrict__ bt,
                                              const float* __restrict__ mask, u16* __restrict__ ao){
  __shared__ __align__(16) u16 KH[64*64];
  __shared__ __align__(16) u16 KL[64*64];
  __shared__ __align__(16) u16 VTs[64*64];
  __shared__ __align__(16) u16 PS[4][16*64];
  int bh = blockIdx.y, b = bh>>4, h = bh&15;
  int q0 = blockIdx.x*64;
  int t = threadIdx.x, w = t>>6, lane = t&63, l16 = lane&15, g = lane>>4;
  size_t base  = (size_t)bh*Sc*64;   // [bh][s][64]
  size_t vbase = (size_t)bh*64*Sc;   // [bh][d][s]
  // Q fragments resident: A[m=lane&15][k=(lane>>4)*8+j], two 32-wide d-steps
  bf16x8 qfh[2], qfl[2];
  {
    int qrow = q0 + w*16 + l16;
    size_t a0 = base + (size_t)qrow*64 + g*8;
    qfh[0] = *(const bf16x8*)&qh[a0];
    qfl[0] = *(const bf16x8*)&ql[a0];
    qfh[1] = *(const bf16x8*)&qh[a0+32];
    qfl[1] = *(const bf16x8*)&ql[a0+32];
  }
  const f32x4 fzero = {0.f,0.f,0.f,0.f};
  f32x4 O[4];
  #pragma unroll
  for(int j=0;j<4;j++) O[j] = fzero;
  float mrow[4] = {-1e30f,-1e30f,-1e30f,-1e30f};
  float lrow[4] = {0.f,0.f,0.f,0.f};
  const float* btr = bt + h*4096;
  int qg[4];
  #pragma unroll
  for(int r=0;r<4;r++) qg[r] = q0 + w*16 + g*4 + r;

  for(int k0=0;k0<Sc;k0+=64){
    __syncthreads();
    #pragma unroll
    for(int jj=0;jj<2;jj++){
      int c = t + 256*jj;
      int row = c>>3, colE = (c&7)*8;
      int lo = row*64 + colE;
      *(uint4*)&KH[lo]  = *(const uint4*)&kh[base + (size_t)(k0+row)*64 + colE];
      *(uint4*)&KL[lo]  = *(const uint4*)&kl[base + (size_t)(k0+row)*64 + colE];
      *(uint4*)&VTs[lo] = *(const uint4*)&vt[vbase + (size_t)row*Sc + k0 + colE];
    }
    __syncthreads();
    // scores: S = Q K^T, split 3-term
    f32x4 sc[4];
    #pragma unroll
    for(int j=0;j<4;j++){
      f32x4 s4 = fzero;
      #pragma unroll
      for(int ds=0; ds<2; ds++){
        int off = (j*16 + l16)*64 + ds*32 + g*8;
        bf16x8 kfh = *(const bf16x8*)&KH[off];
        bf16x8 kfl = *(const bf16x8*)&KL[off];
        s4 = mfma16(qfh[ds], kfh, s4);
        s4 = mfma16(qfh[ds], kfl, s4);
        s4 = mfma16(qfl[ds], kfh, s4);
      }
      sc[j] = s4;
    }
    // bias + mask
    #pragma unroll
    for(int j=0;j<4;j++){
      int kidx = k0 + j*16 + l16;
      float mk = mask[b*Sc + kidx];
      const float* bp = btr + kidx + 2047;
      #pragma unroll
      for(int r=0;r<4;r++){
        sc[j][r] += bp[-qg[r]] + mk;
      }
    }
    // online softmax (rows live on 16-lane groups, reg r = row g*4+r)
    float alp[4], rs[4];
    #pragma unroll
    for(int r=0;r<4;r++){
      float v = fmaxf(fmaxf(sc[0][r],sc[1][r]),fmaxf(sc[2][r],sc[3][r]));
      v = fmaxf(v, __shfl_xor(v,1,64));
      v = fmaxf(v, __shfl_xor(v,2,64));
      v = fmaxf(v, __shfl_xor(v,4,64));
      v = fmaxf(v, __shfl_xor(v,8,64));
      float mn = fmaxf(mrow[r], v);
      alp[r] = expf(mrow[r]-mn);
      mrow[r] = mn;
      rs[r] = 0.f;
    }
    #pragma unroll
    for(int j=0;j<4;j++)
      #pragma unroll
      for(int r=0;r<4;r++){
        float p = expf(sc[j][r]-mrow[r]);
        sc[j][r] = p;
        rs[r] += p;
      }
    #pragma unroll
    for(int r=0;r<4;r++){
      float v = rs[r];
      v += __shfl_xor(v,1,64);
      v += __shfl_xor(v,2,64);
      v += __shfl_xor(v,4,64);
      v += __shfl_xor(v,8,64);
      lrow[r] = lrow[r]*alp[r] + v;
    }
    #pragma unroll
    for(int jd=0;jd<4;jd++)
      #pragma unroll
      for(int r=0;r<4;r++) O[jd][r] *= alp[r];
    // P: C-layout -> LDS -> A-layout
    u16* ps = &PS[w][0];
    #pragma unroll
    for(int j=0;j<4;j++)
      #pragma unroll
      for(int r=0;r<4;r++)
        ps[(g*4+r)*64 + j*16 + l16] = f2b(sc[j][r]);
    #pragma unroll
    for(int ds=0; ds<2; ds++){
      bf16x8 pa = *(const bf16x8*)&ps[l16*64 + ds*32 + g*8];
      #pragma unroll
      for(int jd=0;jd<4;jd++){
        bf16x8 vb = *(const bf16x8*)&VTs[(jd*16 + l16)*64 + ds*32 + g*8];
        O[jd] = mfma16(pa, vb, O[jd]);
      }
    }
  }
  // epilogue -> attn_out [b][s][h*64+d] bf16
  #pragma unroll
  for(int r=0;r<4;r++){
    float inv = 1.f/lrow[r];
    size_t a = ((size_t)(b*Sc + qg[r]))*1024 + h*64;
    #pragma unroll
    for(int jd=0;jd<4;jd++)
      ao[a + jd*16 + l16] = f2b(O[jd][r]*inv);
  }
}

// ---------------- output projection ----------------
__global__ __launch_bounds__(256) void k_gemm_out(const u16* __restrict__ ao, const u16* __restrict__ wot,
                                                  float* __restrict__ out){
  __shared__ __align__(16) u16 As[128*32];
  __shared__ __align__(16) u16 Bs[128*32];
  int m0 = blockIdx.y*128, n0 = blockIdx.x*128;
  int t = threadIdx.x, w = t>>6, lane = t&63, l16 = lane&15, g = lane>>4;
  const f32x4 fzero = {0.f,0.f,0.f,0.f};
  f32x4 acc[4][4];
  #pragma unroll
  for(int i=0;i<4;i++)
    #pragma unroll
    for(int j=0;j<4;j++) acc[i][j] = fzero;
  int rbase = (w>>1)*64, cbase = (w&1)*64;
  for(int k0=0;k0<1024;k0+=32){
    __syncthreads();
    #pragma unroll
    for(int jj=0;jj<2;jj++){
      int c = t + 256*jj;
      int row = c>>2, colE = (c&3)*8;
      int lo = row*32 + colE;
      *(uint4*)&As[lo] = *(const uint4*)&ao[(size_t)(m0+row)*1024 + k0 + colE];
      *(uint4*)&Bs[lo] = *(const uint4*)&wot[(size_t)(n0+row)*1024 + k0 + colE];
    }
    __syncthreads();
    bf16x8 af[4];
    #pragma unroll
    for(int i=0;i<4;i++){
      int off = (rbase + i*16 + l16)*32 + g*8;
      af[i] = *(const bf16x8*)&As[off];
    }
    #pragma unroll
    for(int j=0;j<4;j++){
      int off = (cbase + j*16 + l16)*32 + g*8;
      bf16x8 bfb = *(const bf16x8*)&Bs[off];
      #pragma unroll
      for(int i=0;i<4;i++)
        acc[i][j] = mfma16(af[i], bfb, acc[i][j]);
    }
  }
  #pragma unroll
  for(int i=0;i<4;i++)
    #pragma unroll
    for(int j=0;j<4;j++)
      #pragma unroll
      for(int r=0;r<4;r++){
        int m = m0 + rbase + i*16 + g*4 + r;
        int n = n0 + cbase + j*16 + l16;
        out[(size_t)m*1024 + n] = acc[i][j][r];
      }
}

// ---------------- launch ----------------
extern "C" void kernel_launch(void* const* d_in, const int* in_sizes, int n_in,
                              void* d_out, int out_size, void* d_ws, size_t ws_size,
                              hipStream_t stream) {
  const float* x   = (const float*)d_in[0];
  const float* Wq  = (const float*)d_in[1];
  const float* Wk  = (const float*)d_in[2];
  const float* Wv  = (const float*)d_in[3];
  const float* Wo  = (const float*)d_in[4];
  const float* rel = (const float*)d_in[5];
  const float* msk = (const float*)d_in[6];
  float* out = (float*)d_out;
  float* bias_out = out + (size_t)4194304;   // B*S*D
  char* ws = (char*)d_ws;
  // ws layout (bytes)
  u16* xh  = (u16*)(ws + 0);          // 8 MB
  u16* xl  = (u16*)(ws + 8388608);    // 8 MB
  u16* wth = (u16*)(ws + 16777216);   // 3 x 2 MB
  u16* wtl = (u16*)(ws + 23068672);   // 3 x 2 MB
  u16* wot = (u16*)(ws + 29360128);   // 2 MB
  u16* qh  = (u16*)(ws + 31457280);   // 8 MB
  u16* ql  = (u16*)(ws + 39845888);   // 8 MB
  u16* kh  = (u16*)(ws + 48234496);   // 8 MB
  u16* kl  = (u16*)(ws + 56623104);   // 8 MB
  u16* vt  = (u16*)(ws + 65011712);   // 8 MB
  u16* ao  = (u16*)(ws + 73400320);   // 8 MB
  float* bt = (float*)(ws + 81788928);// 256 KB

  k_convert_x <<<4096, 256, 0, stream>>>(x, xh, xl);
  k_convert_w <<<dim3(16,16,4), 256, 0, stream>>>(Wq, Wk, Wv, Wo, wth, wtl, wot);
  k_bias_table<<<256, 256, 0, stream>>>(rel, bt);
  k_write_bias<<<65536, 256, 0, stream>>>(bt, bias_out);
  k_gemm_qkv  <<<dim3(8,32,3), 256, 0, stream>>>(xh, xl, wth, wtl, qh, ql, kh, kl, vt);
  k_attn      <<<dim3(32,32), 256, 0, stream>>>(qh, ql, kh, kl, vt, bt, msk, ao);
  k_gemm_out  <<<dim3(8,32), 256, 0, stream>>>(ao, wot, out);
}

// Round 2
// 540.194 us; speedup vs baseline: 1.2527x; 1.2527x over previous
//
#include <hip/hip_runtime.h>
#include <hip/hip_bf16.h>
#include <math.h>
#include <stdint.h>

typedef __bf16 bf16_t;
typedef __attribute__((ext_vector_type(8))) __bf16 bf16x8;
typedef __attribute__((ext_vector_type(4))) float f32x4;
typedef unsigned short u16;
typedef unsigned int u32;

#define DEV static __device__ __forceinline__
#define LOG2E 1.4426950408889634f

DEV u16 f2b(float f){ bf16_t h = (bf16_t)f; return __builtin_bit_cast(u16, h); }
DEV float b2f(u16 u){ bf16_t h = __builtin_bit_cast(bf16_t, u); return (float)h; }
DEV f32x4 mfma16(bf16x8 a, bf16x8 b, f32x4 c){
  return __builtin_amdgcn_mfma_f32_16x16x32_bf16(a, b, c, 0, 0, 0);
}

#if __has_builtin(__builtin_amdgcn_exp2f)
DEV float fexp2(float x){ return __builtin_amdgcn_exp2f(x); }
#else
DEV float fexp2(float x){ return exp2f(x); }
#endif

// async global->LDS, 16B per lane; LDS dest = uniform base + lane*16
DEV void gld16(const void* g, void* l){
  __builtin_amdgcn_global_load_lds((const __attribute__((address_space(1))) u32*)g,
                                   (__attribute__((address_space(3))) u32*)l, 16, 0, 0);
}

// swizzled frag reads. 64-col arrays (attn): 8 chunks/row, phys = ch ^ (row&7)
DEV bf16x8 ldsA64(const u16* arr, int row, int ch){
  return *(const bf16x8*)&arr[row*64 + ((ch ^ (row&7))*8)];
}
// 32-col arrays (gemm): 4 chunks/row, phys = ch ^ ((row>>1)&3)
DEV bf16x8 ldsA32(const u16* arr, int row, int ch){
  return *(const bf16x8*)&arr[row*32 + ((ch ^ ((row>>1)&3))*8)];
}

// ---------------- converts ----------------
__global__ __launch_bounds__(256) void k_convert_x(const float* __restrict__ x,
                                                   u16* __restrict__ xh, u16* __restrict__ xl){
  size_t i = ((size_t)blockIdx.x*256 + threadIdx.x)*4;
  float4 v = *(const float4*)(x + i);
  ushort4 hv, lv; float f, hf;
  f=v.x; hv.x=f2b(f); hf=b2f(hv.x); lv.x=f2b(f-hf);
  f=v.y; hv.y=f2b(f); hf=b2f(hv.y); lv.y=f2b(f-hf);
  f=v.z; hv.z=f2b(f); hf=b2f(hv.z); lv.z=f2b(f-hf);
  f=v.w; hv.w=f2b(f); hf=b2f(hv.w); lv.w=f2b(f-hf);
  *(ushort4*)(xh+i) = hv;
  *(ushort4*)(xl+i) = lv;
}

__global__ __launch_bounds__(256) void k_convert_w(const float* __restrict__ Wq, const float* __restrict__ Wk,
                                                   const float* __restrict__ Wv, const float* __restrict__ Wo,
                                                   u16* __restrict__ wth, u16* __restrict__ wtl,
                                                   u16* __restrict__ wot){
  __shared__ float tile[64][65];
  int z = blockIdx.z;
  const float* W = (z==0)?Wq:((z==1)?Wk:((z==2)?Wv:Wo));
  int n0 = blockIdx.x*64, k0 = blockIdx.y*64;
  int t = threadIdx.x;
  int r = t>>6, c = t&63;
  #pragma unroll
  for(int i=0;i<16;i++){
    int row = i*4 + r;
    tile[row][c] = W[(size_t)(k0+row)*1024 + n0 + c];
  }
  __syncthreads();
  #pragma unroll
  for(int i=0;i<16;i++){
    int nrow = i*4 + r;
    float v = tile[c][nrow];
    size_t o = (size_t)(n0+nrow)*1024 + k0 + c;
    u16 hb = f2b(v);
    if(z<3){
      wth[(size_t)z*1048576 + o] = hb;
      wtl[(size_t)z*1048576 + o] = f2b(v - b2f(hb));
    } else {
      wot[o] = hb;
    }
  }
}

// ---------------- bias tables ----------------
__global__ __launch_bounds__(256) void k_bias_table(const float* __restrict__ rel_table,
                                                    const float* __restrict__ mask,
                                                    float* __restrict__ bt, float* __restrict__ bt2,
                                                    float* __restrict__ msk2){
  int gid = blockIdx.x*256 + threadIdx.x;   // 16*4096
  if(gid < 4096) msk2[gid] = mask[gid]*LOG2E;
  int h = gid >> 12, idx = gid & 4095;
  float v = 0.f;
  if(idx < 4095){
    int delta = idx - 2047;   // k - q
    int n = -delta;
    int ret = 0;
    if(n < 0){ ret = 16; n = -n; }
    int bucket;
    if(n < 8) bucket = n + ret;
    else {
      float a = (float)log((double)n * 0.125);
      float rr = (float)((double)a / (double)2.7725887298583984f);
      int vl = 8 + (int)(rr * 8.0f);
      vl = vl > 15 ? 15 : vl;
      bucket = vl + ret;
    }
    v = rel_table[bucket*16 + h];
  }
  bt[gid] = v;
  bt2[gid] = v*LOG2E - 32.0f;
}

__global__ __launch_bounds__(256) void k_write_bias(const float* __restrict__ bt,
                                                    float* __restrict__ out){
  size_t f = ((size_t)blockIdx.x*256 + threadIdx.x)*4;
  int h = (int)(f >> 22);
  int rem = (int)(f & 4194303);
  int q = rem >> 11;
  int k = rem & 2047;
  const float* row = bt + h*4096 + (k - q + 2047);
  float4 v = make_float4(row[0], row[1], row[2], row[3]);
  *(float4*)(out + f) = v;
}

// ---------------- QKV projection GEMM (split-bf16 x3) ----------------
__global__ __launch_bounds__(256) void k_gemm_qkv(const u16* __restrict__ xh, const u16* __restrict__ xl,
                                                  const u16* __restrict__ wth, const u16* __restrict__ wtl,
                                                  u16* __restrict__ qh, u16* __restrict__ ql,
                                                  u16* __restrict__ kh, u16* __restrict__ kl,
                                                  u16* __restrict__ vt){
  // staging: Ah[0..4096) Al[4096..) Bh[8192..) Bl[12288..); CT transpose aliases [0..17408)
  __shared__ __align__(16) u16 SM[17408];
  u16* Ah = SM; u16* Al = SM+4096; u16* Bh = SM+8192; u16* Bl = SM+12288;
  int z = blockIdx.z;
  const u16* WH = wth + (size_t)z*1048576;
  const u16* WL = wtl + (size_t)z*1048576;
  int m0 = blockIdx.y*128, n0 = blockIdx.x*128;
  int t = threadIdx.x, w = t>>6, lane = t&63, l16 = lane&15, g = lane>>4;
  const f32x4 fzero = {0.f,0.f,0.f,0.f};
  f32x4 acc[4][4];
  #pragma unroll
  for(int i=0;i<4;i++)
    #pragma unroll
    for(int j=0;j<4;j++) acc[i][j] = fzero;
  int rbase = (w>>1)*64, cbase = (w&1)*64;
  for(int k0=0;k0<1024;k0+=32){
    __syncthreads();
    #pragma unroll
    for(int jj=0;jj<8;jj++){
      int q = w + 4*jj;            // chunk id 0..31
      int arr = q>>3, sub = q&7;
      int row = sub*16 + (lane>>2);
      int lch = (lane&3) ^ ((row>>1)&3);
      const u16* src;
      if(arr==0)      src = xh + (size_t)(m0+row)*1024 + k0 + lch*8;
      else if(arr==1) src = xl + (size_t)(m0+row)*1024 + k0 + lch*8;
      else if(arr==2) src = WH + (size_t)(n0+row)*1024 + k0 + lch*8;
      else            src = WL + (size_t)(n0+row)*1024 + k0 + lch*8;
      gld16(src, &SM[q*512]);
    }
    __syncthreads();
    bf16x8 ah[4], am[4];
    #pragma unroll
    for(int i=0;i<4;i++){
      int row = rbase + i*16 + l16;
      ah[i] = ldsA32(Ah, row, g);
      am[i] = ldsA32(Al, row, g);
    }
    #pragma unroll
    for(int j=0;j<4;j++){
      int row = cbase + j*16 + l16;
      bf16x8 bh = ldsA32(Bh, row, g);
      bf16x8 bl = ldsA32(Bl, row, g);
      #pragma unroll
      for(int i=0;i<4;i++){
        acc[i][j] = mfma16(ah[i], bh, acc[i][j]);
        acc[i][j] = mfma16(ah[i], bl, acc[i][j]);
        acc[i][j] = mfma16(am[i], bh, acc[i][j]);
      }
    }
  }
  if(z==2){
    // V: transpose via LDS (stride 136, +8 pad: 2-way free), coalesced 16B stores
    __syncthreads();
    #pragma unroll
    for(int i=0;i<4;i++)
      #pragma unroll
      for(int j=0;j<4;j++)
        #pragma unroll
        for(int r=0;r<4;r++){
          int ml = rbase + i*16 + g*4 + r;        // local m
          int nl = cbase + j*16 + l16;            // local n
          SM[nl*136 + ml] = f2b(acc[i][j][r]);
        }
    __syncthreads();
    int bb = m0 >> 11;
    #pragma unroll
    for(int kk=0;kk<8;kk++){
      int id = t + 256*kk;
      int row = id>>4, ch = id&15;                 // row: local n, ch: 8-elem m chunk
      uint4 v = *(const uint4*)&SM[row*136 + ch*8];
      int n = n0 + row;
      size_t dst = ((size_t)(bb*16 + (n>>6))*64 + (n&63))*2048 + (m0&2047) + ch*8;
      *(uint4*)&vt[dst] = v;
    }
  } else {
    #pragma unroll
    for(int i=0;i<4;i++)
      #pragma unroll
      for(int j=0;j<4;j++)
        #pragma unroll
        for(int r=0;r<4;r++){
          int m = m0 + rbase + i*16 + g*4 + r;
          int n = n0 + cbase + j*16 + l16;
          float v = acc[i][j][r];
          if(z==0) v *= LOG2E;                    // fold log2e into Q for exp2 softmax
          int b = m >> 11, s = m & 2047;
          int hh = n >> 6, d = n & 63;
          size_t a = ((size_t)(b*16+hh)*2048 + s)*64 + d;
          u16 hb = f2b(v);
          u16 lb = f2b(v - b2f(hb));
          if(z==0){ qh[a]=hb; ql[a]=lb; }
          else    { kh[a]=hb; kl[a]=lb; }
        }
  }
}

// ---------------- flash attention (max-free exp2 softmax) ----------------
__global__ __launch_bounds__(256) void k_attn(const u16* __restrict__ qh, const u16* __restrict__ ql,
                                              const u16* __restrict__ kh, const u16* __restrict__ kl,
                                              const u16* __restrict__ vt, const float* __restrict__ bt2,
                                              const float* __restrict__ msk2, u16* __restrict__ ao){
  // KH[0..4096) KL[4096..8192) VT[8192..12288) PS[12288..21504) (4 waves x 32x72)
  __shared__ __align__(16) u16 SM[21504];
  u16* KH = SM; u16* KL = SM+4096; u16* VT = SM+8192;
  int bh = blockIdx.y, b = bh>>4, h = bh&15;
  int q0 = blockIdx.x*128;
  int t = threadIdx.x, w = t>>6, lane = t&63, l16 = lane&15, g = lane>>4;
  size_t base  = (size_t)bh*2048*64;   // q/k: [bh][s][64]
  size_t vbase = (size_t)bh*64*2048;   // v^T: [bh][d][s]
  u16* PSw = SM + 12288 + w*2304;
  const float* bt2h = bt2 + h*4096;
  const float* msk2b = msk2 + b*2048;

  // register-resident Q (pre-scaled by log2e)
  bf16x8 qfh[2][2], qfl[2][2];
  #pragma unroll
  for(int i=0;i<2;i++){
    int qr = q0 + w*32 + i*16 + l16;
    size_t a0 = base + (size_t)qr*64 + g*8;
    qfh[i][0] = *(const bf16x8*)&qh[a0];
    qfl[i][0] = *(const bf16x8*)&ql[a0];
    qfh[i][1] = *(const bf16x8*)&qh[a0+32];
    qfl[i][1] = *(const bf16x8*)&ql[a0+32];
  }
  const f32x4 fzero = {0.f,0.f,0.f,0.f};
  f32x4 O[2][4];
  float rs[2][4];
  #pragma unroll
  for(int i=0;i<2;i++){
    #pragma unroll
    for(int jd=0;jd<4;jd++) O[i][jd] = fzero;
    #pragma unroll
    for(int r=0;r<4;r++) rs[i][r] = 0.f;
  }

  for(int k0=0;k0<2048;k0+=64){
    __syncthreads();
    // stage KH/KL/VT: 24 x 1KB DMA chunks, 6 per wave
    #pragma unroll
    for(int jj=0;jj<6;jj++){
      int q = w + 4*jj;
      int arr = q>>3, sub = q&7;
      int row = sub*8 + (lane>>3);
      int lch = (lane&7) ^ (row&7);
      const u16* src;
      if(arr==0)      src = kh + base + (size_t)(k0+row)*64 + lch*8;
      else if(arr==1) src = kl + base + (size_t)(k0+row)*64 + lch*8;
      else            src = vt + vbase + (size_t)row*2048 + k0 + lch*8;
      gld16(src, &SM[q*512]);
    }
    __syncthreads();
    // QK^T, 3-term split
    f32x4 sc[2][4];
    #pragma unroll
    for(int j=0;j<4;j++){
      int krow = j*16 + l16;
      bf16x8 kfh0 = ldsA64(KH, krow, g);
      bf16x8 kfl0 = ldsA64(KL, krow, g);
      bf16x8 kfh1 = ldsA64(KH, krow, 4+g);
      bf16x8 kfl1 = ldsA64(KL, krow, 4+g);
      #pragma unroll
      for(int i=0;i<2;i++){
        f32x4 s = fzero;
        s = mfma16(qfh[i][0], kfh0, s);
        s = mfma16(qfh[i][0], kfl0, s);
        s = mfma16(qfl[i][0], kfh0, s);
        s = mfma16(qfh[i][1], kfh1, s);
        s = mfma16(qfh[i][1], kfl1, s);
        s = mfma16(qfl[i][1], kfh1, s);
        sc[i][j] = s;
      }
    }
    // bias + mask + exp2, write P to LDS
    float mkj[4];
    #pragma unroll
    for(int j=0;j<4;j++) mkj[j] = msk2b[k0 + j*16 + l16];
    #pragma unroll
    for(int i=0;i<2;i++){
      const float* bbase = bt2h + (k0 + l16 + 2047 - (q0 + w*32 + i*16 + g*4));
      #pragma unroll
      for(int j=0;j<4;j++){
        const float* bp = bbase + j*16;
        #pragma unroll
        for(int r=0;r<4;r++){
          float tt = sc[i][j][r] + bp[-r] + mkj[j];
          float p = fexp2(tt);
          rs[i][r] += p;
          PSw[(i*16 + g*4 + r)*72 + j*16 + l16] = f2b(p);
        }
      }
    }
    // PV (P via LDS C->A relayout; PS is wave-private so no barrier)
    #pragma unroll
    for(int ds=0; ds<2; ds++){
      bf16x8 pa0 = *(const bf16x8*)&PSw[(     l16)*72 + ds*32 + g*8];
      bf16x8 pa1 = *(const bf16x8*)&PSw[(16 + l16)*72 + ds*32 + g*8];
      #pragma unroll
      for(int jd=0;jd<4;jd++){
        bf16x8 vb = ldsA64(VT, jd*16 + l16, ds*4 + g);
        O[0][jd] = mfma16(pa0, vb, O[0][jd]);
        O[1][jd] = mfma16(pa1, vb, O[1][jd]);
      }
    }
  }
  // epilogue: l-reduce (within 16-lane groups), normalize, store bf16
  #pragma unroll
  for(int i=0;i<2;i++){
    float inv[4];
    #pragma unroll
    for(int r=0;r<4;r++){
      float v = rs[i][r];
      v += __shfl_xor(v,1,64);
      v += __shfl_xor(v,2,64);
      v += __shfl_xor(v,4,64);
      v += __shfl_xor(v,8,64);
      inv[r] = 1.f/v;
    }
    #pragma unroll
    for(int r=0;r<4;r++){
      int q = q0 + w*32 + i*16 + g*4 + r;
      size_t a = ((size_t)(b*2048 + q))*1024 + h*64;
      #pragma unroll
      for(int jd=0;jd<4;jd++)
        ao[a + jd*16 + l16] = f2b(O[i][jd][r]*inv[r]);
    }
  }
}

// ---------------- output projection ----------------
__global__ __launch_bounds__(256) void k_gemm_out(const u16* __restrict__ ao, const u16* __restrict__ wot,
                                                  float* __restrict__ out){
  __shared__ __align__(16) u16 SM[8192];   // As[0..4096) Bs[4096..8192)
  u16* As = SM; u16* Bs = SM+4096;
  int m0 = blockIdx.y*128, n0 = blockIdx.x*128;
  int t = threadIdx.x, w = t>>6, lane = t&63, l16 = lane&15, g = lane>>4;
  const f32x4 fzero = {0.f,0.f,0.f,0.f};
  f32x4 acc[4][4];
  #pragma unroll
  for(int i=0;i<4;i++)
    #pragma unroll
    for(int j=0;j<4;j++) acc[i][j] = fzero;
  int rbase = (w>>1)*64, cbase = (w&1)*64;
  for(int k0=0;k0<1024;k0+=32){
    __syncthreads();
    #pragma unroll
    for(int jj=0;jj<4;jj++){
      int q = w + 4*jj;            // 16 chunks
      int arr = q>>3, sub = q&7;
      int row = sub*16 + (lane>>2);
      int lch = (lane&3) ^ ((row>>1)&3);
      const u16* src;
      if(arr==0) src = ao  + (size_t)(m0+row)*1024 + k0 + lch*8;
      else       src = wot + (size_t)(n0+row)*1024 + k0 + lch*8;
      gld16(src, &SM[q*512]);
    }
    __syncthreads();
    bf16x8 af[4];
    #pragma unroll
    for(int i=0;i<4;i++) af[i] = ldsA32(As, rbase + i*16 + l16, g);
    #pragma unroll
    for(int j=0;j<4;j++){
      bf16x8 bfb = ldsA32(Bs, cbase + j*16 + l16, g);
      #pragma unroll
      for(int i=0;i<4;i++)
        acc[i][j] = mfma16(af[i], bfb, acc[i][j]);
    }
  }
  #pragma unroll
  for(int i=0;i<4;i++)
    #pragma unroll
    for(int j=0;j<4;j++)
      #pragma unroll
      for(int r=0;r<4;r++){
        int m = m0 + rbase + i*16 + g*4 + r;
        int n = n0 + cbase + j*16 + l16;
        out[(size_t)m*1024 + n] = acc[i][j][r];
      }
}

// ---------------- launch ----------------
extern "C" void kernel_launch(void* const* d_in, const int* in_sizes, int n_in,
                              void* d_out, int out_size, void* d_ws, size_t ws_size,
                              hipStream_t stream) {
  const float* x   = (const float*)d_in[0];
  const float* Wq  = (const float*)d_in[1];
  const float* Wk  = (const float*)d_in[2];
  const float* Wv  = (const float*)d_in[3];
  const float* Wo  = (const float*)d_in[4];
  const float* rel = (const float*)d_in[5];
  const float* msk = (const float*)d_in[6];
  float* out = (float*)d_out;
  float* bias_out = out + (size_t)4194304;   // B*S*D
  char* ws = (char*)d_ws;
  u16* xh  = (u16*)(ws + 0);          // 8 MB
  u16* xl  = (u16*)(ws + 8388608);    // 8 MB
  u16* wth = (u16*)(ws + 16777216);   // 3 x 2 MB
  u16* wtl = (u16*)(ws + 23068672);   // 3 x 2 MB
  u16* wot = (u16*)(ws + 29360128);   // 2 MB
  u16* qh  = (u16*)(ws + 31457280);   // 8 MB
  u16* ql  = (u16*)(ws + 39845888);   // 8 MB
  u16* kh  = (u16*)(ws + 48234496);   // 8 MB
  u16* kl  = (u16*)(ws + 56623104);   // 8 MB
  u16* vt  = (u16*)(ws + 65011712);   // 8 MB
  u16* ao  = (u16*)(ws + 73400320);   // 8 MB
  float* bt   = (float*)(ws + 81788928);  // 256 KB (raw bias, for output)
  float* bt2  = (float*)(ws + 82051072);  // 256 KB (bias*log2e - 32)
  float* msk2 = (float*)(ws + 82313216);  // 16 KB  (mask*log2e)

  k_convert_x <<<4096, 256, 0, stream>>>(x, xh, xl);
  k_convert_w <<<dim3(16,16,4), 256, 0, stream>>>(Wq, Wk, Wv, Wo, wth, wtl, wot);
  k_bias_table<<<256, 256, 0, stream>>>(rel, msk, bt, bt2, msk2);
  k_write_bias<<<65536, 256, 0, stream>>>(bt, bias_out);
  k_gemm_qkv  <<<dim3(8,32,3), 256, 0, stream>>>(xh, xl, wth, wtl, qh, ql, kh, kl, vt);
  k_attn      <<<dim3(16,32), 256, 0, stream>>>(qh, ql, kh, kl, vt, bt2, msk2, ao);
  k_gemm_out  <<<dim3(8,32), 256, 0, stream>>>(ao, wot, out);
}

// Round 3
// 532.155 us; speedup vs baseline: 1.2716x; 1.0151x over previous
//
#include <hip/hip_runtime.h>
#include <hip/hip_bf16.h>
#include <math.h>
#include <stdint.h>

typedef __bf16 bf16_t;
typedef __attribute__((ext_vector_type(8))) __bf16 bf16x8;
typedef __attribute__((ext_vector_type(4))) float f32x4;
typedef unsigned short u16;
typedef unsigned int u32;

#define DEV static __device__ __forceinline__
#define LOG2E 1.4426950408889634f

DEV u16 f2b(float f){ bf16_t h = (bf16_t)f; return __builtin_bit_cast(u16, h); }
DEV float b2f(u16 u){ bf16_t h = __builtin_bit_cast(bf16_t, u); return (float)h; }
DEV f32x4 mfma16(bf16x8 a, bf16x8 b, f32x4 c){
  return __builtin_amdgcn_mfma_f32_16x16x32_bf16(a, b, c, 0, 0, 0);
}

#if __has_builtin(__builtin_amdgcn_exp2f)
DEV float fexp2(float x){ return __builtin_amdgcn_exp2f(x); }
#else
DEV float fexp2(float x){ return exp2f(x); }
#endif

// async global->LDS, 16B per lane; LDS dest = uniform base + lane*16
DEV void gld16(const void* g, void* l){
  __builtin_amdgcn_global_load_lds((const __attribute__((address_space(1))) u32*)g,
                                   (__attribute__((address_space(3))) u32*)l, 16, 0, 0);
}

// swizzled frag reads. 64-col arrays (attn): 8 chunks/row, phys = ch ^ (row&7)
DEV bf16x8 ldsA64(const u16* arr, int row, int ch){
  return *(const bf16x8*)&arr[row*64 + ((ch ^ (row&7))*8)];
}
// 32-col arrays (gemm): 4 chunks/row, phys = ch ^ ((row>>1)&3)
DEV bf16x8 ldsA32(const u16* arr, int row, int ch){
  return *(const bf16x8*)&arr[row*32 + ((ch ^ ((row>>1)&3))*8)];
}

// ---------------- converts ----------------
__global__ __launch_bounds__(256) void k_convert_x(const float* __restrict__ x,
                                                   u16* __restrict__ xh, u16* __restrict__ xl){
  size_t i = ((size_t)blockIdx.x*256 + threadIdx.x)*4;
  float4 v = *(const float4*)(x + i);
  ushort4 hv, lv; float f, hf;
  f=v.x; hv.x=f2b(f); hf=b2f(hv.x); lv.x=f2b(f-hf);
  f=v.y; hv.y=f2b(f); hf=b2f(hv.y); lv.y=f2b(f-hf);
  f=v.z; hv.z=f2b(f); hf=b2f(hv.z); lv.z=f2b(f-hf);
  f=v.w; hv.w=f2b(f); hf=b2f(hv.w); lv.w=f2b(f-hf);
  *(ushort4*)(xh+i) = hv;
  *(ushort4*)(xl+i) = lv;
}

__global__ __launch_bounds__(256) void k_convert_w(const float* __restrict__ Wq, const float* __restrict__ Wk,
                                                   const float* __restrict__ Wv, const float* __restrict__ Wo,
                                                   u16* __restrict__ wth, u16* __restrict__ wtl,
                                                   u16* __restrict__ wot){
  __shared__ float tile[64][65];
  int z = blockIdx.z;
  const float* W = (z==0)?Wq:((z==1)?Wk:((z==2)?Wv:Wo));
  int n0 = blockIdx.x*64, k0 = blockIdx.y*64;
  int t = threadIdx.x;
  int r = t>>6, c = t&63;
  #pragma unroll
  for(int i=0;i<16;i++){
    int row = i*4 + r;
    tile[row][c] = W[(size_t)(k0+row)*1024 + n0 + c];
  }
  __syncthreads();
  #pragma unroll
  for(int i=0;i<16;i++){
    int nrow = i*4 + r;
    float v = tile[c][nrow];
    size_t o = (size_t)(n0+nrow)*1024 + k0 + c;
    u16 hb = f2b(v);
    if(z<3){
      wth[(size_t)z*1048576 + o] = hb;
      wtl[(size_t)z*1048576 + o] = f2b(v - b2f(hb));
    } else {
      wot[o] = hb;
    }
  }
}

// ---------------- bias tables ----------------
__global__ __launch_bounds__(256) void k_bias_table(const float* __restrict__ rel_table,
                                                    const float* __restrict__ mask,
                                                    float* __restrict__ bt, float* __restrict__ bt2,
                                                    float* __restrict__ msk2){
  int gid = blockIdx.x*256 + threadIdx.x;   // 16*4096
  if(gid < 4096) msk2[gid] = mask[gid]*LOG2E;
  int h = gid >> 12, idx = gid & 4095;
  float v = 0.f;
  if(idx < 4095){
    int delta = idx - 2047;   // k - q
    int n = -delta;
    int ret = 0;
    if(n < 0){ ret = 16; n = -n; }
    int bucket;
    if(n < 8) bucket = n + ret;
    else {
      float a = (float)log((double)n * 0.125);
      float rr = (float)((double)a / (double)2.7725887298583984f);
      int vl = 8 + (int)(rr * 8.0f);
      vl = vl > 15 ? 15 : vl;
      bucket = vl + ret;
    }
    v = rel_table[bucket*16 + h];
  }
  bt[gid] = v;
  bt2[gid] = v*LOG2E - 32.0f;
}

__global__ __launch_bounds__(256) void k_write_bias(const float* __restrict__ bt,
                                                    float* __restrict__ out){
  size_t f = ((size_t)blockIdx.x*256 + threadIdx.x)*4;
  int h = (int)(f >> 22);
  int rem = (int)(f & 4194303);
  int q = rem >> 11;
  int k = rem & 2047;
  const float* row = bt + h*4096 + (k - q + 2047);
  float4 v = make_float4(row[0], row[1], row[2], row[3]);
  *(float4*)(out + f) = v;
}

// ---------------- QKV projection GEMM ----------------
// Q,K: split-bf16 x3 terms; V: 1-term (hi only)
__global__ __launch_bounds__(256) void k_gemm_qkv(const u16* __restrict__ xh, const u16* __restrict__ xl,
                                                  const u16* __restrict__ wth, const u16* __restrict__ wtl,
                                                  u16* __restrict__ qh, u16* __restrict__ ql,
                                                  u16* __restrict__ kh, u16* __restrict__ vt){
  __shared__ __align__(16) u16 SM[17408];
  u16* Ah = SM; u16* Al = SM+4096; u16* Bh = SM+8192; u16* Bl = SM+12288;
  int z = blockIdx.z;
  const u16* WH = wth + (size_t)z*1048576;
  const u16* WL = wtl + (size_t)z*1048576;
  int m0 = blockIdx.y*128, n0 = blockIdx.x*128;
  int t = threadIdx.x, w = t>>6, lane = t&63, l16 = lane&15, g = lane>>4;
  const f32x4 fzero = {0.f,0.f,0.f,0.f};
  f32x4 acc[4][4];
  #pragma unroll
  for(int i=0;i<4;i++)
    #pragma unroll
    for(int j=0;j<4;j++) acc[i][j] = fzero;
  int rbase = (w>>1)*64, cbase = (w&1)*64;
  for(int k0=0;k0<1024;k0+=32){
    __syncthreads();
    #pragma unroll
    for(int jj=0;jj<8;jj++){
      int q = w + 4*jj;            // chunk id 0..31
      int arr = q>>3, sub = q&7;
      if(z==2 && (arr&1)) continue;     // V: no lo arrays
      int row = sub*16 + (lane>>2);
      int lch = (lane&3) ^ ((row>>1)&3);
      const u16* src;
      if(arr==0)      src = xh + (size_t)(m0+row)*1024 + k0 + lch*8;
      else if(arr==1) src = xl + (size_t)(m0+row)*1024 + k0 + lch*8;
      else if(arr==2) src = WH + (size_t)(n0+row)*1024 + k0 + lch*8;
      else            src = WL + (size_t)(n0+row)*1024 + k0 + lch*8;
      gld16(src, &SM[q*512]);
    }
    __syncthreads();
    if(z==2){
      bf16x8 ah[4];
      #pragma unroll
      for(int i=0;i<4;i++) ah[i] = ldsA32(Ah, rbase + i*16 + l16, g);
      #pragma unroll
      for(int j=0;j<4;j++){
        bf16x8 bh = ldsA32(Bh, cbase + j*16 + l16, g);
        #pragma unroll
        for(int i=0;i<4;i++)
          acc[i][j] = mfma16(ah[i], bh, acc[i][j]);
      }
    } else {
      bf16x8 ah[4], am[4];
      #pragma unroll
      for(int i=0;i<4;i++){
        int row = rbase + i*16 + l16;
        ah[i] = ldsA32(Ah, row, g);
        am[i] = ldsA32(Al, row, g);
      }
      #pragma unroll
      for(int j=0;j<4;j++){
        int row = cbase + j*16 + l16;
        bf16x8 bh = ldsA32(Bh, row, g);
        bf16x8 bl = ldsA32(Bl, row, g);
        #pragma unroll
        for(int i=0;i<4;i++){
          acc[i][j] = mfma16(ah[i], bh, acc[i][j]);
          acc[i][j] = mfma16(ah[i], bl, acc[i][j]);
          acc[i][j] = mfma16(am[i], bh, acc[i][j]);
        }
      }
    }
  }
  if(z==2){
    // V: transpose via LDS (stride 136, +8 pad), coalesced 16B stores
    __syncthreads();
    #pragma unroll
    for(int i=0;i<4;i++)
      #pragma unroll
      for(int j=0;j<4;j++)
        #pragma unroll
        for(int r=0;r<4;r++){
          int ml = rbase + i*16 + g*4 + r;
          int nl = cbase + j*16 + l16;
          SM[nl*136 + ml] = f2b(acc[i][j][r]);
        }
    __syncthreads();
    int bb = m0 >> 11;
    #pragma unroll
    for(int kk=0;kk<8;kk++){
      int id = t + 256*kk;
      int row = id>>4, ch = id&15;
      uint4 v = *(const uint4*)&SM[row*136 + ch*8];
      int n = n0 + row;
      size_t dst = ((size_t)(bb*16 + (n>>6))*64 + (n&63))*2048 + (m0&2047) + ch*8;
      *(uint4*)&vt[dst] = v;
    }
  } else {
    #pragma unroll
    for(int i=0;i<4;i++)
      #pragma unroll
      for(int j=0;j<4;j++)
        #pragma unroll
        for(int r=0;r<4;r++){
          int m = m0 + rbase + i*16 + g*4 + r;
          int n = n0 + cbase + j*16 + l16;
          float v = acc[i][j][r];
          if(z==0) v *= LOG2E;                    // fold log2e into Q
          int b = m >> 11, s = m & 2047;
          int hh = n >> 6, d = n & 63;
          size_t a = ((size_t)(b*16+hh)*2048 + s)*64 + d;
          u16 hb = f2b(v);
          if(z==0){ qh[a]=hb; ql[a]=f2b(v - b2f(hb)); }
          else    { kh[a]=hb; }
        }
  }
}

// ---------------- flash attention (max-free exp2 softmax, 2-term QK^T) ----------------
__global__ __launch_bounds__(256) void k_attn(const u16* __restrict__ qh, const u16* __restrict__ ql,
                                              const u16* __restrict__ kh,
                                              const u16* __restrict__ vt, const float* __restrict__ bt2,
                                              const float* __restrict__ msk2, u16* __restrict__ ao){
  // KH[0..4096) VT[4096..8192) PS[8192..17408) (4 waves x 32x72)
  __shared__ __align__(16) u16 SM[17408];
  u16* KH = SM; u16* VT = SM+4096;
  int bh = blockIdx.y, b = bh>>4, h = bh&15;
  int q0 = blockIdx.x*128;
  int t = threadIdx.x, w = t>>6, lane = t&63, l16 = lane&15, g = lane>>4;
  size_t base  = (size_t)bh*2048*64;   // q/k: [bh][s][64]
  size_t vbase = (size_t)bh*64*2048;   // v^T: [bh][d][s]
  u16* PSw = SM + 8192 + w*2304;
  const float* bt2h = bt2 + h*4096;
  const float* msk2b = msk2 + b*2048;

  // register-resident Q (pre-scaled by log2e)
  bf16x8 qfh[2][2], qfl[2][2];
  #pragma unroll
  for(int i=0;i<2;i++){
    int qr = q0 + w*32 + i*16 + l16;
    size_t a0 = base + (size_t)qr*64 + g*8;
    qfh[i][0] = *(const bf16x8*)&qh[a0];
    qfl[i][0] = *(const bf16x8*)&ql[a0];
    qfh[i][1] = *(const bf16x8*)&qh[a0+32];
    qfl[i][1] = *(const bf16x8*)&ql[a0+32];
  }
  f32x4 O[2][4];
  float rs[2][4];
  #pragma unroll
  for(int i=0;i<2;i++){
    #pragma unroll
    for(int jd=0;jd<4;jd++) O[i][jd] = {0.f,0.f,0.f,0.f};
    #pragma unroll
    for(int r=0;r<4;r++) rs[i][r] = 0.f;
  }

  for(int k0=0;k0<2048;k0+=64){
    __syncthreads();
    // stage KH/VT: 16 x 1KB DMA chunks, 4 per wave
    #pragma unroll
    for(int jj=0;jj<4;jj++){
      int q = w + 4*jj;
      int arr = q>>3, sub = q&7;
      int row = sub*8 + (lane>>3);
      int lch = (lane&7) ^ (row&7);
      const u16* src;
      if(arr==0) src = kh + base + (size_t)(k0+row)*64 + lch*8;
      else       src = vt + vbase + (size_t)row*2048 + k0 + lch*8;
      gld16(src, &SM[q*512]);
    }
    // init acc with bias+mask (loads overlap the DMA wait)
    float mkj[4];
    #pragma unroll
    for(int j=0;j<4;j++) mkj[j] = msk2b[k0 + j*16 + l16];
    f32x4 sc[2][4];
    #pragma unroll
    for(int i=0;i<2;i++){
      const float* bb = bt2h + (k0 + l16 + 2047 - (q0 + w*32 + i*16 + g*4));
      #pragma unroll
      for(int j=0;j<4;j++){
        #pragma unroll
        for(int r=0;r<4;r++)
          sc[i][j][r] = bb[j*16 - r] + mkj[j];
      }
    }
    __syncthreads();
    // QK^T, 2-term split (qh+ql vs kh)
    #pragma unroll
    for(int j=0;j<4;j++){
      int krow = j*16 + l16;
      bf16x8 kfh0 = ldsA64(KH, krow, g);
      bf16x8 kfh1 = ldsA64(KH, krow, 4+g);
      #pragma unroll
      for(int i=0;i<2;i++){
        f32x4 s = sc[i][j];
        s = mfma16(qfh[i][0], kfh0, s);
        s = mfma16(qfl[i][0], kfh0, s);
        s = mfma16(qfh[i][1], kfh1, s);
        s = mfma16(qfl[i][1], kfh1, s);
        sc[i][j] = s;
      }
    }
    // exp2, accumulate l, write P to LDS
    #pragma unroll
    for(int i=0;i<2;i++){
      #pragma unroll
      for(int j=0;j<4;j++){
        #pragma unroll
        for(int r=0;r<4;r++){
          float p = fexp2(sc[i][j][r]);
          rs[i][r] += p;
          PSw[(i*16 + g*4 + r)*72 + j*16 + l16] = f2b(p);
        }
      }
    }
    // PV (PS is wave-private, no barrier)
    #pragma unroll
    for(int ds=0; ds<2; ds++){
      bf16x8 pa0 = *(const bf16x8*)&PSw[(     l16)*72 + ds*32 + g*8];
      bf16x8 pa1 = *(const bf16x8*)&PSw[(16 + l16)*72 + ds*32 + g*8];
      #pragma unroll
      for(int jd=0;jd<4;jd++){
        bf16x8 vb = ldsA64(VT, jd*16 + l16, ds*4 + g);
        O[0][jd] = mfma16(pa0, vb, O[0][jd]);
        O[1][jd] = mfma16(pa1, vb, O[1][jd]);
      }
    }
  }
  // epilogue: l-reduce (within 16-lane groups), normalize, store bf16
  #pragma unroll
  for(int i=0;i<2;i++){
    float inv[4];
    #pragma unroll
    for(int r=0;r<4;r++){
      float v = rs[i][r];
      v += __shfl_xor(v,1,64);
      v += __shfl_xor(v,2,64);
      v += __shfl_xor(v,4,64);
      v += __shfl_xor(v,8,64);
      inv[r] = 1.f/v;
    }
    #pragma unroll
    for(int r=0;r<4;r++){
      int q = q0 + w*32 + i*16 + g*4 + r;
      size_t a = ((size_t)(b*2048 + q))*1024 + h*64;
      #pragma unroll
      for(int jd=0;jd<4;jd++)
        ao[a + jd*16 + l16] = f2b(O[i][jd][r]*inv[r]);
    }
  }
}

// ---------------- output projection ----------------
__global__ __launch_bounds__(256) void k_gemm_out(const u16* __restrict__ ao, const u16* __restrict__ wot,
                                                  float* __restrict__ out){
  __shared__ __align__(16) u16 SM[8192];
  u16* As = SM; u16* Bs = SM+4096;
  int m0 = blockIdx.y*128, n0 = blockIdx.x*128;
  int t = threadIdx.x, w = t>>6, lane = t&63, l16 = lane&15, g = lane>>4;
  f32x4 acc[4][4];
  #pragma unroll
  for(int i=0;i<4;i++)
    #pragma unroll
    for(int j=0;j<4;j++) acc[i][j] = {0.f,0.f,0.f,0.f};
  int rbase = (w>>1)*64, cbase = (w&1)*64;
  for(int k0=0;k0<1024;k0+=32){
    __syncthreads();
    #pragma unroll
    for(int jj=0;jj<4;jj++){
      int q = w + 4*jj;
      int arr = q>>3, sub = q&7;
      int row = sub*16 + (lane>>2);
      int lch = (lane&3) ^ ((row>>1)&3);
      const u16* src;
      if(arr==0) src = ao  + (size_t)(m0+row)*1024 + k0 + lch*8;
      else       src = wot + (size_t)(n0+row)*1024 + k0 + lch*8;
      gld16(src, &SM[q*512]);
    }
    __syncthreads();
    bf16x8 af[4];
    #pragma unroll
    for(int i=0;i<4;i++) af[i] = ldsA32(As, rbase + i*16 + l16, g);
    #pragma unroll
    for(int j=0;j<4;j++){
      bf16x8 bfb = ldsA32(Bs, cbase + j*16 + l16, g);
      #pragma unroll
      for(int i=0;i<4;i++)
        acc[i][j] = mfma16(af[i], bfb, acc[i][j]);
    }
  }
  #pragma unroll
  for(int i=0;i<4;i++)
    #pragma unroll
    for(int j=0;j<4;j++)
      #pragma unroll
      for(int r=0;r<4;r++){
        int m = m0 + rbase + i*16 + g*4 + r;
        int n = n0 + cbase + j*16 + l16;
        out[(size_t)m*1024 + n] = acc[i][j][r];
      }
}

// ---------------- launch ----------------
extern "C" void kernel_launch(void* const* d_in, const int* in_sizes, int n_in,
                              void* d_out, int out_size, void* d_ws, size_t ws_size,
                              hipStream_t stream) {
  const float* x   = (const float*)d_in[0];
  const float* Wq  = (const float*)d_in[1];
  const float* Wk  = (const float*)d_in[2];
  const float* Wv  = (const float*)d_in[3];
  const float* Wo  = (const float*)d_in[4];
  const float* rel = (const float*)d_in[5];
  const float* msk = (const float*)d_in[6];
  float* out = (float*)d_out;
  float* bias_out = out + (size_t)4194304;   // B*S*D
  char* ws = (char*)d_ws;
  u16* xh  = (u16*)(ws + 0);          // 8 MB
  u16* xl  = (u16*)(ws + 8388608);    // 8 MB
  u16* wth = (u16*)(ws + 16777216);   // 3 x 2 MB
  u16* wtl = (u16*)(ws + 23068672);   // 3 x 2 MB
  u16* wot = (u16*)(ws + 29360128);   // 2 MB
  u16* qh  = (u16*)(ws + 31457280);   // 8 MB
  u16* ql  = (u16*)(ws + 39845888);   // 8 MB
  u16* kh  = (u16*)(ws + 48234496);   // 8 MB
  u16* vt  = (u16*)(ws + 65011712);   // 8 MB
  u16* ao  = (u16*)(ws + 73400320);   // 8 MB
  float* bt   = (float*)(ws + 81788928);  // 256 KB
  float* bt2  = (float*)(ws + 82051072);  // 256 KB
  float* msk2 = (float*)(ws + 82313216);  // 16 KB

  k_convert_x <<<4096, 256, 0, stream>>>(x, xh, xl);
  k_convert_w <<<dim3(16,16,4), 256, 0, stream>>>(Wq, Wk, Wv, Wo, wth, wtl, wot);
  k_bias_table<<<256, 256, 0, stream>>>(rel, msk, bt, bt2, msk2);
  k_write_bias<<<65536, 256, 0, stream>>>(bt, bias_out);
  k_gemm_qkv  <<<dim3(8,32,3), 256, 0, stream>>>(xh, xl, wth, wtl, qh, ql, kh, vt);
  k_attn      <<<dim3(16,32), 256, 0, stream>>>(qh, ql, kh, vt, bt2, msk2, ao);
  k_gemm_out  <<<dim3(8,32), 256, 0, stream>>>(ao, wot, out);
}